// Round 3
// baseline (376.541 us; speedup 1.0000x reference)
//
#include <hip/hip_runtime.h>

typedef unsigned short u16;
typedef __attribute__((ext_vector_type(8)))  short          short8;
typedef __attribute__((ext_vector_type(8)))  unsigned short ushort8v;
typedef __attribute__((ext_vector_type(4)))  unsigned short ushort4v;
typedef __attribute__((ext_vector_type(16))) float          float16v;

__device__ __forceinline__ float bf2f(u16 u){
  union { unsigned int i; float f; } x; x.i = ((unsigned int)u) << 16; return x.f;
}
__device__ __forceinline__ u16 f2bf(float f){
  union { float f; unsigned int i; } x; x.f = f;
  unsigned int u = x.i;
  unsigned int r = (u + 0x7FFFu + ((u >> 16) & 1u)) >> 16;
  return (u16)r;
}
__device__ __forceinline__ float lk(float v){ return v > 0.f ? v : 0.01f*v; }

// ------- weight permute+quantize into MFMA-fragment-TILED layout -------------
// Tile = (32 out-rows) x (one k-step of 16): 512 bf16 = 1 KB, lane-major
// fragments: elem[(tile*64 + lane)*8 + e], lane l holds
// A[row = rb*32 + (l&31)][k = jk*16 + (l>>5)*8 + e].
// ws layout (bf16): L1 @0 (8 rb x 24 jk tiles), L2 @98304 (4 x 48), L3 @196608 (2 x 24)
// SINGLE copy (432 KB): replication was tried and REGRESSED — the extra copies
// pushed the streamed trees + weights past L2/L3 residency (FETCH +48 MB/disp).
__global__ void permute_w(const float* __restrict__ W1, const float* __restrict__ W2,
                          const float* __restrict__ W3, u16* __restrict__ ws){
  int t = blockIdx.x*256 + threadIdx.x;
  const float* src; u16* dst; int C, local;
  if (t < 98304)       { src = W1; dst = ws;          C = 128; local = t; }
  else if (t < 196608) { src = W2; dst = ws + 98304;  C = 256; local = t - 98304; }
  else if (t < 221184) { src = W3; dst = ws + 196608; C = 128; local = t - 196608; }
  else return;
  const int NJK  = 3*C/16;
  const int tile = local >> 9, within = local & 511;
  const int lane = within >> 3, e = within & 7;
  const int rb = tile / NJK, jk = tile - rb*NJK;
  const int o  = rb*32 + (lane & 31);
  const int kg = jk*16 + (lane >> 5)*8 + e;
  const int j  = kg / C, c = kg - j*C;
  dst[local] = f2bf(src[o*3*C + c*3 + j]);
}

// ---------------- fused per-tree layer (8 waves, in-register output) ----------
// GEMM out[O x 127] = W[O x 3C] * G, where G[j*C+c][m] = bIn[idx[3m+j]][c]
// NACT active waves; wave w -> row-block (w*NTL)>>2 (64 rows, PAIR=2 tiles),
// n-tiles (w*NTL)&3..+NTL.  Output stays in acc until after the stats
// __syncthreads (fences k-loop LDS reads), THEN is written to bOut/bOutF —
// which may ALIAS bIn.
//
// K-PHASE ROTATION (per block AND per wave): all resident blocks on an XCD
// march through the same 432 KB weight stream in near-lockstep, so without
// rotation dozens of CUs request the SAME L2 line each cycle -> same-address
// channel serialization -> A-load latency explosion (the measured ~25%-idle
// profile; confirmed by round-2's latency sensitivity). Rotating the k-start
// within each j-segment (phase = f(block, wave)) decorrelates the line
// streams with ZERO extra footprint. Accumulation order within a j-segment
// is reassociated — fp noise ~1e-6, well under the bf16 tolerance.
template<int CIN, int O, int SIN, int OST, int NTL, int NACT, bool LEAKY, bool IS_L3>
__device__ __forceinline__ void do_layer(const u16* __restrict__ Wt,
                                         const float* __restrict__ bias,
                                         const u16* bIn, u16* bOut, float* bOutF,
                                         const int* sidx, float* sstat,
                                         int tid, int phseed,
                                         float* out_mean, float* out_inv)
{
  constexpr int KS  = CIN/16;     // k-steps per j segment (8 or 16)
  constexpr int NJK = 3*KS;       // total k-steps
  static_assert((O/64)*4 == NACT*NTL, "work split mismatch");
  const int w = tid >> 6, lane = tid & 63, l31 = lane & 31, h = lane >> 5;
  const bool active = (w < NACT);
  const int wa = active ? w : 0;  // clamp so inactive waves' pointer math stays in-range

  const int u0  = wa*NTL;
  const int rb  = u0 >> 2;        // 64-row block id
  const int nt0 = u0 & 3;         // first n-tile
  const int r0  = rb * 64;

  // per-block + per-wave k-phase (waves sharing an rb get distinct phases)
  const int ph = (phseed + w*(KS/8)) & (KS - 1);

  // tiled A bases: tile index = (rb*2 + a)*NJK + jk, lane-major inside
  const u16* aP[2] = { Wt + ((size_t)(rb*2    )*NJK)*512 + lane*8,
                       Wt + ((size_t)(rb*2 + 1)*NJK)*512 + lane*8 };

  float16v acc[NTL][2];
  float s = 0.f, s2 = 0.f;

  if (active){
    int boff[NTL][3];
#pragma unroll
    for (int n = 0; n < NTL; ++n){
      int m = (nt0 + n)*32 + l31;   // position 0..127 (127 is pad, masked below)
#pragma unroll
      for (int j = 0; j < 3; ++j){
        int i = sidx[3*m + j];      // m==127 hits zero-padded sidx[381..383]
        boff[n][j] = i*SIN + h*8;
      }
    }

#pragma unroll
    for (int n = 0; n < NTL; ++n){ acc[n][0] = {}; acc[n][1] = {}; }

#pragma unroll
    for (int j = 0; j < 3; ++j){
      int ks = ph;                  // rotated k-step within this j segment
#pragma unroll
      for (int t = 0; t < KS; ++t){
        const int jk   = j*KS + ks;
        const int coff = ks*16;
        short8 A0 = *(const short8*)(aP[0] + jk*512);
        short8 A1 = *(const short8*)(aP[1] + jk*512);
#pragma unroll
        for (int n = 0; n < NTL; ++n){
          short8 Bf = *(const short8*)(bIn + boff[n][j] + coff);
          acc[n][0] = __builtin_amdgcn_mfma_f32_32x32x16_bf16(A0, Bf, acc[n][0], 0, 0, 0);
          acc[n][1] = __builtin_amdgcn_mfma_f32_32x32x16_bf16(A1, Bf, acc[n][1], 0, 0, 0);
        }
        ks = (ks == KS-1) ? 0 : ks + 1;
      }
    }

    // post-loop: bias add (L2-hot, off the k-loop critical path) + stats partials
#pragma unroll
    for (int n = 0; n < NTL; ++n){
      const int m = (nt0 + n)*32 + l31;
      const bool valid = (m <= 126);
#pragma unroll
      for (int a = 0; a < 2; ++a)
#pragma unroll
        for (int g = 0; g < 4; ++g){
          const int rowb = r0 + a*32 + 8*g + 4*h;   // C/D row = (reg&3)+8*(reg>>2)+4h
#pragma unroll
          for (int q = 0; q < 4; ++q){
            float raw = acc[n][a][4*g + q] + bias[rowb + q];
            acc[n][a][4*g + q] = raw;
            if (valid){ s += raw; s2 += raw*raw; }
          }
        }
    }
  }

  // block-wide stats; this __syncthreads also FENCES all k-loop reads of bIn,
  // making it safe for the store phase below to overwrite bIn's region.
#pragma unroll
  for (int off = 32; off >= 1; off >>= 1){
    s  += __shfl_down(s,  off, 64);
    s2 += __shfl_down(s2, off, 64);
  }
  if (lane == 0){ sstat[w*2] = s; sstat[w*2+1] = s2; }
  __syncthreads();

  float tot = 0.f, tot2 = 0.f;
#pragma unroll
  for (int q = 0; q < 8; ++q){ tot += sstat[2*q]; tot2 += sstat[2*q+1]; }
  constexpr float CNT = (float)(O * 128);
  const float mean = tot / CNT;
  float var = (tot2 - tot*mean) / (CNT - 1.f);   // unbiased, ddof=1
  var = fmaxf(var, 0.f);
  const float inv = 1.f / (sqrtf(var) + 1e-5f);
  *out_mean = mean; *out_inv = inv;

  // store phase (may alias the dead input region)
  if constexpr (!IS_L3){
    if (active){
#pragma unroll
      for (int n = 0; n < NTL; ++n){
        const int m = (nt0 + n)*32 + l31;
        const bool valid = (m <= 126);
#pragma unroll
        for (int a = 0; a < 2; ++a){
#pragma unroll
          for (int g = 0; g < 4; ++g){
            const int rowb = r0 + a*32 + 8*g + 4*h;
            ushort4v pk;
#pragma unroll
            for (int q = 0; q < 4; ++q){
              float f = (acc[n][a][4*g + q] - mean) * inv;
              if constexpr (LEAKY) f = lk(f);
              pk[q] = f2bf(f);
            }
            if (valid) *(ushort4v*)(bOut + (size_t)(m+1)*OST + rowb) = pk;
          }
        }
      }
    }
    // node-0 row: normalized zero
    if (tid < O/8){
      float f0 = (0.f - mean) * inv;
      if constexpr (LEAKY) f0 = lk(f0);
      const u16 v0 = f2bf(f0);
      ushort8v z;
#pragma unroll
      for (int e = 0; e < 8; ++e) z[e] = v0;
      *(ushort8v*)(bOut + tid*8) = z;
    }
  } else {
    // raw fp32 (stride OST floats, odd -> conflict-free); maxpool applies
    // (max(raw)-mean)*inv via monotonicity. Node-0 raw == 0 handled by caller.
    if (active){
#pragma unroll
      for (int n = 0; n < NTL; ++n){
        const int m = (nt0 + n)*32 + l31;
        if (m <= 126){
#pragma unroll
          for (int a = 0; a < 2; ++a)
#pragma unroll
            for (int g = 0; g < 4; ++g){
              const int rowb = r0 + a*32 + 8*g + 4*h;
#pragma unroll
              for (int q = 0; q < 4; ++q)
                bOutF[(size_t)(m+1)*OST + rowb + q] = acc[n][a][4*g + q];
            }
        }
      }
    }
  }
  __syncthreads();
}

// LDS: one 66 KB union buffer, reused by every stage:
//   trees in  [128 n][136] bf16   34816 B
//   L1 out    [128 n][264] bf16   67584 B  (over dead trees)
//   L2 out    [128 n][136] bf16   34816 B  (over dead L1)
//   L3 raw    [128 n][67]  fp32   34304 B  (over dead L2)
// 512 threads / 8 waves per block, 2 blocks/CU (LDS-bound) -> 16 waves/CU.
__global__ __launch_bounds__(512, 4) void bao_main(
    const float* __restrict__ trees, const int* __restrict__ gidx,
    const u16* __restrict__ wsW,
    const float* __restrict__ b1, const float* __restrict__ b2, const float* __restrict__ b3,
    const float* __restrict__ W4, const float* __restrict__ b4,
    const float* __restrict__ W5, const float* __restrict__ b5,
    float* __restrict__ dout)
{
  __shared__ __align__(16) u16 buf[33792];      // 67584 B union buffer
  __shared__ int   sidx[384];
  __shared__ float sstat[16];
  __shared__ float spoolP[512];
  __shared__ float spool[64];
  __shared__ float sh[32];

  const int tid = threadIdx.x;
  const int b = blockIdx.x;
  float* bufF = (float*)buf;

  // phase seed: co-resident blocks on one XCD have blockIdx ≡ xcd (mod 8)
  // spaced by 8 -> (b>>3) cycles the k-phase across them.
  const int phseed = (b >> 3) & 15;

  // load + transpose + quantize trees[b] (fp32 [128 c][128 n] -> bf16 buf[n][c]).
  // Packed ds_write_b128; node-stride 17 super-banks => conflict-free.
  const float* tb = trees + (size_t)b * (128*128);
  {
    const int ngrp = tid & 31, cg = tid >> 5;   // cg 0..15
    const int c0 = cg*8;
#pragma unroll
    for (int it = 0; it < 4; ++it){
      const int n = ngrp + 32*it;
      ushort8v pk;
#pragma unroll
      for (int cc = 0; cc < 8; ++cc) pk[cc] = f2bf(tb[(c0 + cc)*128 + n]);
      *(ushort8v*)(buf + n*136 + c0) = pk;
    }
  }
  // idx (381 entries, pad to 384 with 0)
  if (tid < 96){
#pragma unroll
    for (int k = 0; k < 4; ++k){
      int ii = tid*4 + k;
      sidx[ii] = (ii < 381) ? gidx[(size_t)b*381 + ii] : 0;
    }
  }
  __syncthreads();

  float mean, inv;
  //            CIN  O   SIN OST NTL NACT LEAKY IS_L3
  do_layer<128,256,136,264, 2, 8, true ,false>(wsW,          b1, buf, buf, nullptr, sidx, sstat, tid, phseed, &mean, &inv);
  do_layer<256,128,264,136, 1, 8, true ,false>(wsW + 98304,  b2, buf, buf, nullptr, sidx, sstat, tid, phseed, &mean, &inv);
  do_layer<128, 64,136, 67, 1, 4, false,true >(wsW + 196608, b3, buf, nullptr, bufF, sidx, sstat, tid, phseed, &mean, &inv);

  // max-pool over nodes (raw fp32, stride 67); node-0 raw is exactly 0 so the
  // 0.f floor is exact. max(normalized) = (max(raw) - mean)*inv (monotone).
  {
    const int ch = tid & 63, seg = tid >> 6;    // seg 0..7, 16 nodes each
    float mx = 0.f;
    const int nd0 = seg*16 + (seg == 0 ? 1 : 0);
    for (int nd = nd0; nd < seg*16 + 16; ++nd) mx = fmaxf(mx, bufF[nd*67 + ch]);
    spoolP[seg*64 + ch] = mx;
  }
  __syncthreads();
  if (tid < 64){
    float mx = spoolP[tid];
#pragma unroll
    for (int k = 1; k < 8; ++k) mx = fmaxf(mx, spoolP[64*k + tid]);
    spool[tid] = (mx - mean) * inv;
  }
  __syncthreads();
  if (tid < 32){
    float a = b4[tid];
    for (int c = 0; c < 64; ++c) a += spool[c] * W4[tid*64 + c];
    sh[tid] = lk(a);
  }
  __syncthreads();
  if (tid == 0){
    float o = b5[0];
    for (int i = 0; i < 32; ++i) o += sh[i] * W5[i];
    dout[b] = o;
  }
}

extern "C" void kernel_launch(void* const* d_in, const int* in_sizes, int n_in,
                              void* d_out, int out_size, void* d_ws, size_t ws_size,
                              hipStream_t stream) {
  const float* trees = (const float*)d_in[0];
  const int*   gidx  = (const int*)d_in[1];
  const float* W1 = (const float*)d_in[2];
  const float* b1 = (const float*)d_in[3];
  const float* W2 = (const float*)d_in[4];
  const float* b2 = (const float*)d_in[5];
  const float* W3 = (const float*)d_in[6];
  const float* b3 = (const float*)d_in[7];
  const float* W4 = (const float*)d_in[8];
  const float* b4 = (const float*)d_in[9];
  const float* W5 = (const float*)d_in[10];
  const float* b5 = (const float*)d_in[11];
  u16* wsW = (u16*)d_ws;   // 221184 bf16 elems = 432 KB of tiled+quantized weights

  permute_w<<<864, 256, 0, stream>>>(W1, W2, W3, wsW);
  bao_main<<<2048, 512, 0, stream>>>(trees, gidx, wsW, b1, b2, b3, W4, b4, W5, b5,
                                     (float*)d_out);
}

// Round 4
// 363.030 us; speedup vs baseline: 1.0372x; 1.0372x over previous
//
#include <hip/hip_runtime.h>

typedef unsigned short u16;
typedef __attribute__((ext_vector_type(8)))  short          short8;
typedef __attribute__((ext_vector_type(8)))  unsigned short ushort8v;
typedef __attribute__((ext_vector_type(4)))  unsigned short ushort4v;
typedef __attribute__((ext_vector_type(16))) float          float16v;

__device__ __forceinline__ float bf2f(u16 u){
  union { unsigned int i; float f; } x; x.i = ((unsigned int)u) << 16; return x.f;
}
__device__ __forceinline__ u16 f2bf(float f){
  union { float f; unsigned int i; } x; x.f = f;
  unsigned int u = x.i;
  unsigned int r = (u + 0x7FFFu + ((u >> 16) & 1u)) >> 16;
  return (u16)r;
}
__device__ __forceinline__ float lk(float v){ return v > 0.f ? v : 0.01f*v; }

// ------- weight permute+quantize into MFMA-fragment-TILED layout -------------
// Tile = (32 out-rows) x (one k-step of 16): 512 bf16 = 1 KB, lane-major
// fragments: elem[(tile*64 + lane)*8 + e], lane l holds
// A[row = rb*32 + (l&31)][k = jk*16 + (l>>5)*8 + e].
// ws layout (bf16): L1 @0 (8 rb x 24 jk tiles), L2 @98304 (4 x 48), L3 @196608 (2 x 24)
// Single copy (432 KB, L2-resident). Replication regressed (capacity);
// k-phase rotation regressed (runtime indices -> scratch spill).
__global__ void permute_w(const float* __restrict__ W1, const float* __restrict__ W2,
                          const float* __restrict__ W3, u16* __restrict__ ws){
  int t = blockIdx.x*256 + threadIdx.x;
  const float* src; u16* dst; int C, local;
  if (t < 98304)       { src = W1; dst = ws;          C = 128; local = t; }
  else if (t < 196608) { src = W2; dst = ws + 98304;  C = 256; local = t - 98304; }
  else if (t < 221184) { src = W3; dst = ws + 196608; C = 128; local = t - 196608; }
  else return;
  const int NJK  = 3*C/16;
  const int tile = local >> 9, within = local & 511;
  const int lane = within >> 3, e = within & 7;
  const int rb = tile / NJK, jk = tile - rb*NJK;
  const int o  = rb*32 + (lane & 31);
  const int kg = jk*16 + (lane >> 5)*8 + e;
  const int j  = kg / C, c = kg - j*C;
  dst[local] = f2bf(src[o*3*C + c*3 + j]);
}

// ---------------- fused per-tree layer, TWO trees per block ------------------
// GEMM out[O x 127] = W[O x 3C] * G per tree; each A fragment pair loaded ONCE
// feeds both trees' B fragments (2x arithmetic intensity on the A stream --
// the measured critical path), and A L2 traffic halves. 8 waves, 1 block/CU,
// 256-reg/wave budget (launch_bounds 512,2) so the compiler can pipeline the
// A/B loads across k-steps (the 128-reg config left only 64 VGPRs -> serial
// load->MFMA chain, MfmaUtil stuck at 25%).
// Output stays in acc until after the stats __syncthreads (fences k-loop LDS
// reads), THEN is written to bOut/bOutF -- which may ALIAS bIn.
template<int CIN, int O, int SIN, int OST, int NTL, int NACT, bool LEAKY, bool IS_L3>
__device__ __forceinline__ void do_layer2(const u16* __restrict__ Wt,
                                          const float* __restrict__ bias,
                                          const u16* bIn0, const u16* bIn1,
                                          u16* bOut0, u16* bOut1,
                                          float* bOutF0, float* bOutF1,
                                          const int* sidx0, const int* sidx1,
                                          float* sstat, int tid,
                                          float* mean2, float* inv2)
{
  constexpr int KS  = CIN/16;     // k-steps per j segment
  constexpr int NJK = 3*KS;       // total k-steps
  static_assert((O/64)*4 == NACT*NTL, "work split mismatch");
  const int w = tid >> 6, lane = tid & 63, l31 = lane & 31, h = lane >> 5;
  const bool active = (w < NACT);
  const int wa = active ? w : 0;  // clamp so inactive waves' pointer math stays in-range

  const int u0  = wa*NTL;
  const int rb  = u0 >> 2;        // 64-row block id
  const int nt0 = u0 & 3;         // first n-tile
  const int r0  = rb * 64;

  // tiled A bases: tile index = (rb*2 + a)*NJK + jk, lane-major inside
  const u16* aP0 = Wt + ((size_t)(rb*2    )*NJK)*512 + lane*8;
  const u16* aP1 = Wt + ((size_t)(rb*2 + 1)*NJK)*512 + lane*8;

  float16v acc[2][NTL][2];
  float s[2] = {0.f, 0.f}, s2[2] = {0.f, 0.f};

  if (active){
    int boff[2][NTL][3];
#pragma unroll
    for (int n = 0; n < NTL; ++n){
      int m = (nt0 + n)*32 + l31;   // position 0..127 (127 is pad, masked below)
#pragma unroll
      for (int j = 0; j < 3; ++j){
        boff[0][n][j] = sidx0[3*m + j]*SIN + h*8;  // m==127 hits zero-padded sidx
        boff[1][n][j] = sidx1[3*m + j]*SIN + h*8;
      }
    }

#pragma unroll
    for (int t = 0; t < 2; ++t)
#pragma unroll
      for (int n = 0; n < NTL; ++n){ acc[t][n][0] = {}; acc[t][n][1] = {}; }

#pragma unroll
    for (int jk = 0; jk < NJK; ++jk){
      const int j    = jk / KS;
      const int coff = (jk - j*KS)*16;
      short8 A0 = *(const short8*)(aP0 + jk*512);
      short8 A1 = *(const short8*)(aP1 + jk*512);
#pragma unroll
      for (int t = 0; t < 2; ++t){
        const u16* bb = t ? bIn1 : bIn0;          // compile-time after unroll
#pragma unroll
        for (int n = 0; n < NTL; ++n){
          short8 Bf = *(const short8*)(bb + boff[t][n][j] + coff);
          acc[t][n][0] = __builtin_amdgcn_mfma_f32_32x32x16_bf16(A0, Bf, acc[t][n][0], 0, 0, 0);
          acc[t][n][1] = __builtin_amdgcn_mfma_f32_32x32x16_bf16(A1, Bf, acc[t][n][1], 0, 0, 0);
        }
      }
    }

    // post-loop: bias add (L2-hot, off the k-loop critical path) + stats partials
#pragma unroll
    for (int t = 0; t < 2; ++t)
#pragma unroll
      for (int n = 0; n < NTL; ++n){
        const int m = (nt0 + n)*32 + l31;
        const bool valid = (m <= 126);
#pragma unroll
        for (int a = 0; a < 2; ++a)
#pragma unroll
          for (int g = 0; g < 4; ++g){
            const int rowb = r0 + a*32 + 8*g + 4*h;   // C/D row = (reg&3)+8*(reg>>2)+4h
#pragma unroll
            for (int q = 0; q < 4; ++q){
              float raw = acc[t][n][a][4*g + q] + bias[rowb + q];
              acc[t][n][a][4*g + q] = raw;
              if (valid){ s[t] += raw; s2[t] += raw*raw; }
            }
          }
      }
  }

  // block-wide stats; this __syncthreads also FENCES all k-loop reads of bIn,
  // making it safe for the store phase below to overwrite bIn's region.
#pragma unroll
  for (int off = 32; off >= 1; off >>= 1){
#pragma unroll
    for (int t = 0; t < 2; ++t){
      s[t]  += __shfl_down(s[t],  off, 64);
      s2[t] += __shfl_down(s2[t], off, 64);
    }
  }
  if (lane == 0){
    sstat[w*4 + 0] = s[0];  sstat[w*4 + 1] = s2[0];
    sstat[w*4 + 2] = s[1];  sstat[w*4 + 3] = s2[1];
  }
  __syncthreads();

#pragma unroll
  for (int t = 0; t < 2; ++t){
    float tot = 0.f, tot2 = 0.f;
#pragma unroll
    for (int q = 0; q < 8; ++q){ tot += sstat[q*4 + t*2]; tot2 += sstat[q*4 + t*2 + 1]; }
    constexpr float CNT = (float)(O * 128);
    const float mean = tot / CNT;
    float var = (tot2 - tot*mean) / (CNT - 1.f);   // unbiased, ddof=1
    var = fmaxf(var, 0.f);
    const float inv = 1.f / (sqrtf(var) + 1e-5f);
    mean2[t] = mean; inv2[t] = inv;
  }

  // store phase (may alias the dead input region)
  if constexpr (!IS_L3){
    if (active){
#pragma unroll
      for (int t = 0; t < 2; ++t){
        u16* bo = t ? bOut1 : bOut0;
        const float mean = mean2[t], inv = inv2[t];
#pragma unroll
        for (int n = 0; n < NTL; ++n){
          const int m = (nt0 + n)*32 + l31;
          const bool valid = (m <= 126);
#pragma unroll
          for (int a = 0; a < 2; ++a){
#pragma unroll
            for (int g = 0; g < 4; ++g){
              const int rowb = r0 + a*32 + 8*g + 4*h;
              ushort4v pk;
#pragma unroll
              for (int q = 0; q < 4; ++q){
                float f = (acc[t][n][a][4*g + q] - mean) * inv;
                if constexpr (LEAKY) f = lk(f);
                pk[q] = f2bf(f);
              }
              if (valid) *(ushort4v*)(bo + (size_t)(m+1)*OST + rowb) = pk;
            }
          }
        }
      }
    }
    // node-0 row: normalized zero (both trees)
    if (tid < O/8){
#pragma unroll
      for (int t = 0; t < 2; ++t){
        float f0 = (0.f - mean2[t]) * inv2[t];
        if constexpr (LEAKY) f0 = lk(f0);
        const u16 v0 = f2bf(f0);
        ushort8v z;
#pragma unroll
        for (int e = 0; e < 8; ++e) z[e] = v0;
        *(ushort8v*)((t ? bOut1 : bOut0) + tid*8) = z;
      }
    }
  } else {
    // raw fp32 (stride OST floats, odd -> conflict-free); maxpool applies
    // (max(raw)-mean)*inv via monotonicity. Node-0 raw == 0 handled by caller.
    if (active){
#pragma unroll
      for (int t = 0; t < 2; ++t){
        float* bo = t ? bOutF1 : bOutF0;
#pragma unroll
        for (int n = 0; n < NTL; ++n){
          const int m = (nt0 + n)*32 + l31;
          if (m <= 126){
#pragma unroll
            for (int a = 0; a < 2; ++a)
#pragma unroll
              for (int g = 0; g < 4; ++g){
                const int rowb = r0 + a*32 + 8*g + 4*h;
#pragma unroll
                for (int q = 0; q < 4; ++q)
                  bo[(size_t)(m+1)*OST + rowb + q] = acc[t][n][a][4*g + q];
              }
          }
        }
      }
    }
  }
  __syncthreads();
}

// LDS: two 66 KB union buffers (one per tree), each reused by every stage:
//   trees in  [128 n][136] bf16   34816 B
//   L1 out    [128 n][264] bf16   67584 B  (over dead trees)
//   L2 out    [128 n][136] bf16   34816 B  (over dead L1)
//   L3 raw    [128 n][67]  fp32   34304 B  (over dead L2)
// 512 threads / 8 waves, ~141 KB LDS -> 1 block/CU, 256-reg/wave budget.
__global__ __launch_bounds__(512, 2) void bao_main(
    const float* __restrict__ trees, const int* __restrict__ gidx,
    const u16* __restrict__ wsW,
    const float* __restrict__ b1, const float* __restrict__ b2, const float* __restrict__ b3,
    const float* __restrict__ W4, const float* __restrict__ b4,
    const float* __restrict__ W5, const float* __restrict__ b5,
    float* __restrict__ dout)
{
  __shared__ __align__(16) u16 buf0[33792];     // 67584 B union buffer, tree 0
  __shared__ __align__(16) u16 buf1[33792];     // 67584 B union buffer, tree 1
  __shared__ int   sidx[2][384];
  __shared__ float sstat[32];
  __shared__ float spoolP[2][256];
  __shared__ float spool[2][64];
  __shared__ float sh[2][32];

  const int tid = threadIdx.x;
  const int b0 = blockIdx.x * 2;
  float* bufF0 = (float*)buf0;
  float* bufF1 = (float*)buf1;

  // load + transpose + quantize both trees (fp32 [128 c][128 n] -> bf16 buf[n][c]).
  // Threads 0-255 stage tree 0, 256-511 stage tree 1 (each wave-quad coalesced).
  {
    const int half = tid >> 8, t2 = tid & 255;
    const float* tb = trees + (size_t)(b0 + half) * (128*128);
    u16* bufS = half ? buf1 : buf0;
    const int ngrp = t2 & 31, cg = t2 >> 5;     // cg 0..7
#pragma unroll
    for (int it = 0; it < 8; ++it){
      const int n  = ngrp + 32*(it & 3);
      const int c0 = (cg + 8*(it >> 2))*8;
      ushort8v pk;
#pragma unroll
      for (int cc = 0; cc < 8; ++cc) pk[cc] = f2bf(tb[(c0 + cc)*128 + n]);
      *(ushort8v*)(bufS + n*136 + c0) = pk;
    }
  }
  // idx (381 entries per tree, pad to 384 with 0)
  if (tid < 192){
    const int tr = tid / 96, bt = tid - tr*96;
#pragma unroll
    for (int k = 0; k < 4; ++k){
      int ii = bt*4 + k;
      sidx[tr][ii] = (ii < 381) ? gidx[(size_t)(b0 + tr)*381 + ii] : 0;
    }
  }
  __syncthreads();

  float mean2[2], inv2[2];
  //             CIN  O   SIN OST NTL NACT LEAKY IS_L3
  do_layer2<128,256,136,264, 2, 8, true ,false>(wsW,          b1, buf0, buf1, buf0, buf1,
                                                nullptr, nullptr, sidx[0], sidx[1],
                                                sstat, tid, mean2, inv2);
  do_layer2<256,128,264,136, 1, 8, true ,false>(wsW + 98304,  b2, buf0, buf1, buf0, buf1,
                                                nullptr, nullptr, sidx[0], sidx[1],
                                                sstat, tid, mean2, inv2);
  do_layer2<128, 64,136, 67, 1, 4, false,true >(wsW + 196608, b3, buf0, buf1, nullptr, nullptr,
                                                bufF0, bufF1, sidx[0], sidx[1],
                                                sstat, tid, mean2, inv2);

  // max-pool over nodes (raw fp32, stride 67); node-0 raw is exactly 0 so the
  // 0.f floor is exact. max(normalized) = (max(raw) - mean)*inv (monotone).
  {
    const int tr = tid >> 8, t2 = tid & 255;
    const int ch = t2 & 63, seg = t2 >> 6;      // seg 0..3, 32 nodes each
    const float* bF = tr ? bufF1 : bufF0;
    float mx = 0.f;
    const int nd0 = seg*32 + (seg == 0 ? 1 : 0);
    for (int nd = nd0; nd < seg*32 + 32; ++nd) mx = fmaxf(mx, bF[nd*67 + ch]);
    spoolP[tr][seg*64 + ch] = mx;
  }
  __syncthreads();
  if (tid < 128){
    const int tr = tid >> 6, ch = tid & 63;
    float mx = fmaxf(fmaxf(spoolP[tr][ch], spoolP[tr][64 + ch]),
                     fmaxf(spoolP[tr][128 + ch], spoolP[tr][192 + ch]));
    spool[tr][ch] = (mx - mean2[tr]) * inv2[tr];
  }
  __syncthreads();
  if (tid < 64){
    const int tr = tid >> 5, r = tid & 31;
    float a = b4[r];
    for (int c = 0; c < 64; ++c) a += spool[tr][c] * W4[r*64 + c];
    sh[tr][r] = lk(a);
  }
  __syncthreads();
  if (tid < 2){
    float o = b5[0];
    for (int i = 0; i < 32; ++i) o += sh[tid][i] * W5[i];
    dout[b0 + tid] = o;
  }
}

extern "C" void kernel_launch(void* const* d_in, const int* in_sizes, int n_in,
                              void* d_out, int out_size, void* d_ws, size_t ws_size,
                              hipStream_t stream) {
  const float* trees = (const float*)d_in[0];
  const int*   gidx  = (const int*)d_in[1];
  const float* W1 = (const float*)d_in[2];
  const float* b1 = (const float*)d_in[3];
  const float* W2 = (const float*)d_in[4];
  const float* b2 = (const float*)d_in[5];
  const float* W3 = (const float*)d_in[6];
  const float* b3 = (const float*)d_in[7];
  const float* W4 = (const float*)d_in[8];
  const float* b4 = (const float*)d_in[9];
  const float* W5 = (const float*)d_in[10];
  const float* b5 = (const float*)d_in[11];
  u16* wsW = (u16*)d_ws;   // 221184 bf16 elems = 432 KB of tiled+quantized weights

  permute_w<<<864, 256, 0, stream>>>(W1, W2, W3, wsW);
  bao_main<<<1024, 512, 0, stream>>>(trees, gidx, wsW, b1, b2, b3, W4, b4, W5, b5,
                                     (float*)d_out);
}

// Round 5
// 330.140 us; speedup vs baseline: 1.1405x; 1.0996x over previous
//
#include <hip/hip_runtime.h>

typedef unsigned short u16;
typedef __attribute__((ext_vector_type(8)))  short          short8;
typedef __attribute__((ext_vector_type(8)))  unsigned short ushort8v;
typedef __attribute__((ext_vector_type(4)))  unsigned short ushort4v;
typedef __attribute__((ext_vector_type(16))) float          float16v;

__device__ __forceinline__ float bf2f(u16 u){
  union { unsigned int i; float f; } x; x.i = ((unsigned int)u) << 16; return x.f;
}
// scalar fallback (node-0 broadcast only) — RNE, identical to v_cvt_pk_bf16_f32
__device__ __forceinline__ u16 f2bf(float f){
  union { float f; unsigned int i; } x; x.f = f;
  unsigned int u = x.i;
  unsigned int r = (u + 0x7FFFu + ((u >> 16) & 1u)) >> 16;
  return (u16)r;
}
// HW packed f32x2 -> bf16x2 (RNE), 1 VALU op for 2 elements (vs ~8 for the
// bit-trick pair). dst.lo = cvt(lo), dst.hi = cvt(hi).
__device__ __forceinline__ unsigned int cvtpk_bf16(float lo, float hi){
  unsigned int r;
  asm("v_cvt_pk_bf16_f32 %0, %1, %2" : "=v"(r) : "v"(lo), "v"(hi));
  return r;
}
// leaky-relu, branchless: x>0 -> x > 0.01x ; x<=0 -> 0.01x >= x
__device__ __forceinline__ float lk(float v){ return fmaxf(v, 0.01f*v); }

// ------- weight permute+quantize into MFMA-fragment-TILED layout -------------
// Tile = (32 out-rows) x (one k-step of 16): 512 bf16 = 1 KB, stored as
// lane-major fragments: elem[(tile*64 + lane)*8 + e], where lane l holds
// A[row = rb*32 + (l&31)][k = jk*16 + (l>>5)*8 + e].  A-loads in the k-loop
// become ONE fully-coalesced 1 KB burst per instruction.
// ws layout (bf16): L1 @0 (8 rb x 24 jk tiles), L2 @98304 (4 x 48), L3 @196608 (2 x 24)
// Single copy (432 KB, L2-resident). Probes that FAILED: 8x replication
// (capacity regression), k-phase rotation (scratch spill), 512-thr occupancy
// (null), 2-tree A-share at 1 blk/CU (lost phase overlap, +20us).
__global__ void permute_w(const float* __restrict__ W1, const float* __restrict__ W2,
                          const float* __restrict__ W3, u16* __restrict__ ws){
  int t = blockIdx.x*256 + threadIdx.x;
  const float* src; u16* dst; int C, local;
  if (t < 98304)       { src = W1; dst = ws;          C = 128; local = t; }
  else if (t < 196608) { src = W2; dst = ws + 98304;  C = 256; local = t - 98304; }
  else if (t < 221184) { src = W3; dst = ws + 196608; C = 128; local = t - 196608; }
  else return;
  const int NJK  = 3*C/16;
  const int tile = local >> 9, within = local & 511;
  const int lane = within >> 3, e = within & 7;
  const int rb = tile / NJK, jk = tile - rb*NJK;
  const int o  = rb*32 + (lane & 31);
  const int kg = jk*16 + (lane >> 5)*8 + e;
  const int j  = kg / C, c = kg - j*C;
  dst[local] = f2bf(src[o*3*C + c*3 + j]);
}

// ---------------- fused per-tree layer (4 waves, in-register output) ----------
// GEMM out[O x 127] = W[O x 3C] * G, where G[j*C+c][m] = bIn[idx[3m+j]][c]
// Wave w -> row-block (w*NTL)>>2 (64 rows, PAIR=2 tiles), n-tiles (w*NTL)&3..+NTL.
// Output stays in acc until after the stats __syncthreads (fences k-loop LDS
// reads), THEN is written to bOut/bOutF — which may ALIAS bIn.
template<int CIN, int O, int SIN, int OST, int NTL, bool LEAKY, bool IS_L3>
__device__ __forceinline__ void do_layer(const u16* __restrict__ Wt,
                                         const float* __restrict__ bias,
                                         const u16* bIn, u16* bOut, float* bOutF,
                                         const int* sidx, float* sstat,
                                         int tid, float* out_mean, float* out_inv)
{
  constexpr int KS  = CIN/16;     // k-steps per j segment
  constexpr int NJK = 3*KS;       // total k-steps
  static_assert((O/64)*4 == 4*NTL, "work split mismatch");
  const int w = tid >> 6, lane = tid & 63, l31 = lane & 31, h = lane >> 5;

  const int u0  = w*NTL;
  const int rb  = u0 >> 2;        // 64-row block id
  const int nt0 = u0 & 3;         // first n-tile
  const int r0  = rb * 64;

  // tiled A bases: tile index = (rb*2 + a)*NJK + jk, lane-major inside
  const u16* aP[2] = { Wt + ((size_t)(rb*2    )*NJK)*512 + lane*8,
                       Wt + ((size_t)(rb*2 + 1)*NJK)*512 + lane*8 };

  int boff[NTL][3];
#pragma unroll
  for (int n = 0; n < NTL; ++n){
    int m = (nt0 + n)*32 + l31;   // position 0..127 (127 is pad, masked below)
#pragma unroll
    for (int j = 0; j < 3; ++j){
      int i = sidx[3*m + j];      // m==127 hits zero-padded sidx[381..383]
      boff[n][j] = i*SIN + h*8;
    }
  }

  float16v acc[NTL][2];
#pragma unroll
  for (int n = 0; n < NTL; ++n){ acc[n][0] = {}; acc[n][1] = {}; }

#pragma unroll
  for (int jk = 0; jk < NJK; ++jk){
    const int j    = jk / KS;
    const int coff = (jk - j*KS)*16;
    short8 A0 = *(const short8*)(aP[0] + jk*512);
    short8 A1 = *(const short8*)(aP[1] + jk*512);
#pragma unroll
    for (int n = 0; n < NTL; ++n){
      short8 Bf = *(const short8*)(bIn + boff[n][j] + coff);
      acc[n][0] = __builtin_amdgcn_mfma_f32_32x32x16_bf16(A0, Bf, acc[n][0], 0, 0, 0);
      acc[n][1] = __builtin_amdgcn_mfma_f32_32x32x16_bf16(A1, Bf, acc[n][1], 0, 0, 0);
    }
  }

  // post-loop: bias add (L2-hot, off the k-loop critical path) + stats partials
  float s = 0.f, s2 = 0.f;
#pragma unroll
  for (int n = 0; n < NTL; ++n){
    const int m = (nt0 + n)*32 + l31;
    const bool valid = (m <= 126);
#pragma unroll
    for (int a = 0; a < 2; ++a)
#pragma unroll
      for (int g = 0; g < 4; ++g){
        const int rowb = r0 + a*32 + 8*g + 4*h;   // C/D row = (reg&3)+8*(reg>>2)+4h
#pragma unroll
        for (int q = 0; q < 4; ++q){
          float raw = acc[n][a][4*g + q] + bias[rowb + q];
          acc[n][a][4*g + q] = raw;
          if (valid){ s += raw; s2 += raw*raw; }
        }
      }
  }

  // block-wide stats; this __syncthreads also FENCES all k-loop reads of bIn,
  // making it safe for the store phase below to overwrite bIn's region.
#pragma unroll
  for (int off = 32; off >= 1; off >>= 1){
    s  += __shfl_down(s,  off, 64);
    s2 += __shfl_down(s2, off, 64);
  }
  if (lane == 0){ sstat[w*2] = s; sstat[w*2+1] = s2; }
  __syncthreads();

  const float tot  = sstat[0] + sstat[2] + sstat[4] + sstat[6];
  const float tot2 = sstat[1] + sstat[3] + sstat[5] + sstat[7];
  constexpr float CNT = (float)(O * 128);
  const float mean = tot / CNT;
  float var = (tot2 - tot*mean) / (CNT - 1.f);   // unbiased, ddof=1
  var = fmaxf(var, 0.f);
  const float inv = 1.f / (sqrtf(var) + 1e-5f);
  *out_mean = mean; *out_inv = inv;

  // store phase (may alias the dead input region)
  if constexpr (!IS_L3){
#pragma unroll
    for (int n = 0; n < NTL; ++n){
      const int m = (nt0 + n)*32 + l31;
      const bool valid = (m <= 126);
#pragma unroll
      for (int a = 0; a < 2; ++a){
#pragma unroll
        for (int g = 0; g < 4; ++g){
          const int rowb = r0 + a*32 + 8*g + 4*h;
          float f[4];
#pragma unroll
          for (int q = 0; q < 4; ++q){
            float v = (acc[n][a][4*g + q] - mean) * inv;
            if constexpr (LEAKY) v = lk(v);
            f[q] = v;
          }
          union { ushort4v v; unsigned int d[2]; } pk;
          pk.d[0] = cvtpk_bf16(f[0], f[1]);
          pk.d[1] = cvtpk_bf16(f[2], f[3]);
          if (valid) *(ushort4v*)(bOut + (size_t)(m+1)*OST + rowb) = pk.v;
        }
      }
    }
    // node-0 row: normalized zero
    if (tid < O/8){
      float f0 = (0.f - mean) * inv;
      if constexpr (LEAKY) f0 = lk(f0);
      const u16 v0 = f2bf(f0);
      ushort8v z;
#pragma unroll
      for (int e = 0; e < 8; ++e) z[e] = v0;
      *(ushort8v*)(bOut + tid*8) = z;
    }
  } else {
    // raw fp32 (stride OST floats, odd -> conflict-free); maxpool applies
    // (max(raw)-mean)*inv via monotonicity. Node-0 raw == 0 handled by caller.
#pragma unroll
    for (int n = 0; n < NTL; ++n){
      const int m = (nt0 + n)*32 + l31;
      if (m <= 126){
#pragma unroll
        for (int a = 0; a < 2; ++a)
#pragma unroll
          for (int g = 0; g < 4; ++g){
            const int rowb = r0 + a*32 + 8*g + 4*h;
#pragma unroll
            for (int q = 0; q < 4; ++q)
              bOutF[(size_t)(m+1)*OST + rowb + q] = acc[n][a][4*g + q];
          }
      }
    }
  }
  __syncthreads();
}

// LDS: one 66 KB union buffer, reused by every stage:
//   trees in  [128 n][136] bf16   34816 B
//   L1 out    [128 n][264] bf16   67584 B  (over dead trees)
//   L2 out    [128 n][136] bf16   34816 B  (over dead L1)
//   L3 raw    [128 n][67]  fp32   34304 B  (over dead L2)
// 256 threads / 4 waves, 2 blocks/CU (phase-offset overlap between the two
// resident blocks measured better than 1x512-thr or 1-blk 2-tree variants).
__global__ __launch_bounds__(256, 2) void bao_main(
    const float* __restrict__ trees, const int* __restrict__ gidx,
    const u16* __restrict__ wsW,
    const float* __restrict__ b1, const float* __restrict__ b2, const float* __restrict__ b3,
    const float* __restrict__ W4, const float* __restrict__ b4,
    const float* __restrict__ W5, const float* __restrict__ b5,
    float* __restrict__ dout)
{
  __shared__ __align__(16) u16 buf[33792];      // 67584 B union buffer
  __shared__ int   sidx[384];
  __shared__ float sstat[8];
  __shared__ float spoolP[256];
  __shared__ float spool[64];
  __shared__ float sh[32];

  const int tid = threadIdx.x;
  const int b = blockIdx.x;
  float* bufF = (float*)buf;

  // load + transpose + quantize trees[b] (fp32 [128 c][128 n] -> bf16 buf[n][c]).
  // Packed ds_write_b128; HW cvt_pk for the f32->bf16 pack.
  const float* tb = trees + (size_t)b * (128*128);
  {
    const int ngrp = tid & 31, cg = tid >> 5;
#pragma unroll
    for (int it = 0; it < 8; ++it){
      const int n  = ngrp + 32*(it & 3);
      const int c0 = (cg + 8*(it >> 2))*8;
      float fv[8];
#pragma unroll
      for (int cc = 0; cc < 8; ++cc) fv[cc] = tb[(c0 + cc)*128 + n];
      union { ushort8v v; unsigned int d[4]; } pk;
#pragma unroll
      for (int p = 0; p < 4; ++p) pk.d[p] = cvtpk_bf16(fv[2*p], fv[2*p+1]);
      *(ushort8v*)(buf + n*136 + c0) = pk.v;
    }
  }
  // idx (381 entries, pad to 384 with 0)
  if (tid < 96){
#pragma unroll
    for (int k = 0; k < 4; ++k){
      int ii = tid*4 + k;
      sidx[ii] = (ii < 381) ? gidx[(size_t)b*381 + ii] : 0;
    }
  }
  __syncthreads();

  float mean, inv;
  //            CIN  O   SIN OST NTL LEAKY IS_L3
  do_layer<128,256,136,264, 4, true ,false>(wsW,          b1, buf, buf, nullptr, sidx, sstat, tid, &mean, &inv);
  do_layer<256,128,264,136, 2, true ,false>(wsW + 98304,  b2, buf, buf, nullptr, sidx, sstat, tid, &mean, &inv);
  do_layer<128, 64,136, 67, 1, false,true >(wsW + 196608, b3, buf, nullptr, bufF, sidx, sstat, tid, &mean, &inv);

  // max-pool over nodes (raw fp32, stride 67); node-0 raw is exactly 0 so the
  // 0.f floor is exact. max(normalized) = (max(raw) - mean)*inv (monotone).
  {
    const int ch = tid & 63, seg = tid >> 6;
    float mx = 0.f;
    const int nd0 = seg*32 + (seg == 0 ? 1 : 0);
    for (int nd = nd0; nd < seg*32 + 32; ++nd) mx = fmaxf(mx, bufF[nd*67 + ch]);
    spoolP[seg*64 + ch] = mx;
  }
  __syncthreads();
  if (tid < 64){
    float mx = fmaxf(fmaxf(spoolP[tid], spoolP[64 + tid]),
                     fmaxf(spoolP[128 + tid], spoolP[192 + tid]));
    spool[tid] = (mx - mean) * inv;
  }
  __syncthreads();
  if (tid < 32){
    float a = b4[tid];
    for (int c = 0; c < 64; ++c) a += spool[c] * W4[tid*64 + c];
    sh[tid] = lk(a);
  }
  __syncthreads();
  if (tid == 0){
    float o = b5[0];
    for (int i = 0; i < 32; ++i) o += sh[i] * W5[i];
    dout[b] = o;
  }
}

extern "C" void kernel_launch(void* const* d_in, const int* in_sizes, int n_in,
                              void* d_out, int out_size, void* d_ws, size_t ws_size,
                              hipStream_t stream) {
  const float* trees = (const float*)d_in[0];
  const int*   gidx  = (const int*)d_in[1];
  const float* W1 = (const float*)d_in[2];
  const float* b1 = (const float*)d_in[3];
  const float* W2 = (const float*)d_in[4];
  const float* b2 = (const float*)d_in[5];
  const float* W3 = (const float*)d_in[6];
  const float* b3 = (const float*)d_in[7];
  const float* W4 = (const float*)d_in[8];
  const float* b4 = (const float*)d_in[9];
  const float* W5 = (const float*)d_in[10];
  const float* b5 = (const float*)d_in[11];
  u16* wsW = (u16*)d_ws;   // 221184 bf16 elems = 432 KB of tiled+quantized weights

  permute_w<<<864, 256, 0, stream>>>(W1, W2, W3, wsW);
  bao_main<<<2048, 256, 0, stream>>>(trees, gidx, wsW, b1, b2, b3, W4, b4, W5, b5,
                                     (float*)d_out);
}